// Round 14
// baseline (215.053 us; speedup 1.0000x reference)
//
#include <hip/hip_runtime.h>
#include <math.h>

// B=32, R=16384, C=16, IC=16, OC=16, 3 routing iterations.
// x: (B,C,IC) fp32 [8192]; W: (R,C,OC,IC) fp32 [67108864 = 256 MB]; out: (B,C,OC) fp32.
//
// Algebra: logits are linear in v with the same u_hat each pass:
//   L2 = <u, v1>,  L3 = L2 + <u, v2> = <u, v1 + v2>
// so pass 3 is the SAME kernel as pass 2 fed with vs = v1 + v2 -> no L history.
//
// R14: COALESCED staging.  R10/R11/R13 all pinned at ~90us/pass with the
// fragment permutation applied to the GLOBAL address: every load's 64 lanes
// hit 16B granules at 64B stride across two rows (~32 cache-line segments
// per instruction, 8x request amplification).  k_wsum's consecutive-lane
// pattern streams the same bytes in ~15us.  Now each global_load_lds stages
// one FULL contiguous 1KB row (lane l -> f4 l); the fragment permutation
// moves to the LDS READ, conflict-free via 65-f4 padded rows:
//   read idx = r'*65 + o*4 + 2hi + n -> granule group (mod 8) =
//   (m>>4) + 4(m&1) + 2hi + n = all 8 groups x 8 lanes (optimal b128).
// Skeleton unchanged from R13: ring-2 wave-private FIFOs, 4 blocks/CU,
// counted vmcnt(2), zero main-loop barriers.

typedef __attribute__((ext_vector_type(8)))  short short8;
typedef __attribute__((ext_vector_type(16))) float f32x16;

union FU { short8 s; unsigned int u[4]; };

typedef const __attribute__((address_space(1))) void GV;
typedef __attribute__((address_space(3))) void LV;

// Split two fp32 into packed bf16 (hi, lo) pairs: hi = RNE-bf16; lo covers
// the next 16 bits (round-half-up).  Product w*x reconstructed with 4 MFMA
// terms -> residual ~2^-16 relative.
__device__ __forceinline__ void splitpk(float a, float b,
                                        unsigned int& hp, unsigned int& lp) {
    unsigned int ua = __float_as_uint(a), ub = __float_as_uint(b);
    unsigned int ta = ua + 0x7FFFu + ((ua >> 16) & 1u);   // RNE to bf16
    unsigned int tb = ub + 0x7FFFu + ((ub >> 16) & 1u);
    hp = (ta >> 16) | (tb & 0xFFFF0000u);                 // (hi_b<<16)|hi_a
    float ha = __uint_as_float(ta & 0xFFFF0000u);
    float hb = __uint_as_float(tb & 0xFFFF0000u);
    unsigned int la = __float_as_uint(a - ha) + 0x8000u;  // round-half-up
    unsigned int lb = __float_as_uint(b - hb) + 0x8000u;
    lp = (la >> 16) | (lb & 0xFFFF0000u);
}

// ---------------------------------------------------------------------------
// K0: zero the accumulator region (wsum+E2+Z2+E3+Z3 = 21504 floats).
// ---------------------------------------------------------------------------
__global__ __launch_bounds__(256) void k_zero(float* __restrict__ ws) {
    ws[blockIdx.x * 256 + threadIdx.x] = 0.f;      // grid 84 x 256 = 21504
}

// ---------------------------------------------------------------------------
// K1: wsum[c,o,i] = sum_r W[r,c,o,i].  W = 16,777,216 float4s.
// ---------------------------------------------------------------------------
__global__ __launch_bounds__(256) void k_wsum(const float4* __restrict__ W4,
                                              float* __restrict__ wsum) {
    int gid = blockIdx.x * 256 + threadIdx.x;      // [0, 262144)
    float4 acc = {0.f, 0.f, 0.f, 0.f};
    int idx = gid;
    #pragma unroll
    for (int it = 0; it < 64; ++it) {              // 16777216 / 262144 = 64
        float4 w = W4[idx];
        acc.x += w.x; acc.y += w.y; acc.z += w.z; acc.w += w.w;
        idx += 262144;
    }
    int cls = gid & 1023;                          // (c,o,i4) within an r-block
    atomicAdd(&wsum[cls * 4 + 0], acc.x);
    atomicAdd(&wsum[cls * 4 + 1], acc.y);
    atomicAdd(&wsum[cls * 4 + 2], acc.z);
    atomicAdd(&wsum[cls * 4 + 3], acc.w);
}

// ---------------------------------------------------------------------------
// K2: s1 = (1/R) * wsum . x ;  v1 = squash(s1)  -> v1[b*256 + c*16 + o]
// ---------------------------------------------------------------------------
__global__ __launch_bounds__(256) void k_v1(const float* __restrict__ wsum,
                                            const float* __restrict__ x,
                                            float* __restrict__ v1) {
    int t = blockIdx.x * 256 + threadIdx.x;        // 0..8191
    int o = t & 15, c = (t >> 4) & 15, b = t >> 8;
    const float* xb = x + (b * 16 + c) * 16;
    const float* wr = wsum + (c * 16 + o) * 16;
    float s = 0.f;
    #pragma unroll
    for (int i = 0; i < 16; ++i) s += wr[i] * xb[i];
    s *= (1.0f / 16384.0f);
    float ns = s * s;
    #pragma unroll
    for (int d = 1; d < 16; d <<= 1) ns += __shfl_xor(ns, d);
    v1[t] = s * (sqrtf(ns) / (1.0f + ns));
}

// ---------------------------------------------------------------------------
// K4a: v2 = squash(E/Z); vs = v1 + v2   (input to pass 3)
// ---------------------------------------------------------------------------
__global__ __launch_bounds__(256) void k_vout_vs(const float* __restrict__ E,
                                                 const float* __restrict__ Z,
                                                 const float* __restrict__ v1,
                                                 float* __restrict__ vs) {
    int t = blockIdx.x * 256 + threadIdx.x;        // 0..8191
    float s = E[t] / Z[t >> 4];                    // t>>4 = b*16+c
    float ns = s * s;
    #pragma unroll
    for (int d = 1; d < 16; d <<= 1) ns += __shfl_xor(ns, d);
    vs[t] = v1[t] + s * (sqrtf(ns) / (1.0f + ns));
}

// ---------------------------------------------------------------------------
// K4b: out = squash(E/Z)
// ---------------------------------------------------------------------------
__global__ __launch_bounds__(256) void k_vout(const float* __restrict__ E,
                                              const float* __restrict__ Z,
                                              float* __restrict__ dst) {
    int t = blockIdx.x * 256 + threadIdx.x;        // 0..8191
    float s = E[t] / Z[t >> 4];
    float ns = s * s;
    #pragma unroll
    for (int d = 1; d < 16; d <<= 1) ns += __shfl_xor(ns, d);
    dst[t] = s * (sqrtf(ns) / (1.0f + ns));
}

// ---------------------------------------------------------------------------
// K3: MFMA routing pass, coalesced staging + padded-LDS fragment reads.
//   Block (bx, c): rows [256bx, +256) x capsule c; 16 chunks of 16 rows;
//   wave wv owns rows {chunk*16 + wv*2, +1} (wave-private FIFO).
//   STAGE = 2 x global_load_lds, each one FULL row: lane l reads f4 l of a
//   contiguous 1 KB run (k_wsum's pattern); dest = padded LDS row (65 f4).
//   ds_read (fragment side): lane (hi,m) reads idx r'*65 + o*4 + 2hi + n,
//   n=0,1 -> conflict-free (8 granule-groups x 8 lanes each).
//   MFMA as R10-R13: A row m=(r'<<4)|o, k-slice 8hi..8hi+7; B = x (lane=b);
//   C col=b, row-reg o=(reg&3)+4hi+8((reg>>2)&1), r'=reg>>3.
//   Lv = 8 in-lane FMAs + ONE shfl_xor(32); accZ pair-duplicated.
// Ring-2 ledger per wave (no barriers): prologue stages 0,1; iter k:
//   vmcnt(2) -> ds_read -> lgkmcnt(0) -> STAGE(k&1, k+2) [k<=13] -> compute.
// LDS 37 KB -> 4 blocks/CU, whole grid co-resident (c-aggregation kept).
// ---------------------------------------------------------------------------
__global__ __launch_bounds__(512)
void k_iter(const float* __restrict__ W,
            const float* __restrict__ x,
            const float* __restrict__ v,
            float* __restrict__ E,
            float* __restrict__ Z) {
    __shared__ float4 Wr[2 * 1040];                // 2 slots x 8 wv x 2 rows x 65 f4
    __shared__ float sV[512];                      // v[b][o] for this c
    __shared__ float E_lds[512];                   // block-level E[b][o]
    __shared__ float Z_lds[32];

    int c = blockIdx.y;
    int r0 = blockIdx.x * 256;
    int tid = threadIdx.x, wv = tid >> 6, l = tid & 63;
    int m  = l & 31;                               // A-row / b-col
    int hi = l >> 5;                               // k-slice select

    // stage v + zero the block reduction buffers
    { int b = tid >> 4, o = tid & 15;
      sV[tid] = v[b * 256 + c * 16 + o];
      E_lds[tid] = 0.f; }
    if (tid < 32) Z_lds[tid] = 0.f;

    // B-fragment (x), chunk-invariant: lane b=m, i = 8*hi + 0..7
    FU bh, bl;
    {
        const float4* xb = (const float4*)x + m * 64 + c * 4 + hi * 2;
        float4 x0 = xb[0], x1 = xb[1];
        splitpk(x0.x, x0.y, bh.u[0], bl.u[0]);
        splitpk(x0.z, x0.w, bh.u[1], bl.u[1]);
        splitpk(x1.x, x1.y, bh.u[2], bl.u[2]);
        splitpk(x1.z, x1.w, bh.u[3], bl.u[3]);
    }
    __syncthreads();                               // sV ready (written cross-lane)

    // v-fragment matching C rows: vf[reg] = v[b = m][o(reg)]
    float vf[16];
    #pragma unroll
    for (int reg = 0; reg < 16; ++reg) {
        int o = (reg & 3) + 4 * hi + 8 * ((reg >> 2) & 1);
        vf[reg] = sV[m * 16 + o];
    }

    float accE[16];
    #pragma unroll
    for (int reg = 0; reg < 16; ++reg) accE[reg] = 0.f;
    float accZ = 0.f;

    // pin vmcnt=0 so the counted waits below are exact (x/sV loads retired)
    asm volatile("s_waitcnt vmcnt(0)" ::: "memory");

    const float4* W4c = (const float4*)W + (size_t)c * 64;   // row (r,c) at +r*1024

    // STAGE: wave wv stages its 2 rows of chunk cn, COALESCED (lane l -> f4 l
    // of the contiguous 64-f4 row); dest = padded 65-f4 LDS rows.
#define STAGE(sl, cn) {                                                        \
        const float4* s0 = W4c +                                               \
            (size_t)(r0 + (cn) * 16 + wv * 2) * 1024 + l;                      \
        __builtin_amdgcn_global_load_lds((GV*)s0,                              \
            (LV*)&Wr[(sl) * 1040 + wv * 130], 16, 0, 0);                       \
        __builtin_amdgcn_global_load_lds((GV*)(s0 + 1024),                     \
            (LV*)&Wr[(sl) * 1040 + wv * 130 + 65], 16, 0, 0);                  \
    }

    STAGE(0, 0); STAGE(1, 1);                      // 4 issues in flight

    // fragment read base: r'=m>>4 row (65 f4 stride), o=m&15, k-slice 2hi
    int rbase = wv * 130 + (m >> 4) * 65 + (m & 15) * 4 + hi * 2;

    #pragma unroll
    for (int chunk = 0; chunk < 16; ++chunk) {
        // retire THIS wave's loads for chunk k; k+1's stay in flight
        if (chunk < 15) asm volatile("s_waitcnt vmcnt(2)" ::: "memory");
        else            asm volatile("s_waitcnt vmcnt(0)" ::: "memory");

        int sb = (chunk & 1) * 1040 + rbase;
        float4 ca = Wr[sb];                        // ds_read_b128, conflict-free
        float4 cb = Wr[sb + 1];

        // slot reuse safety: reads retired before the DMA refill below
        asm volatile("s_waitcnt lgkmcnt(0)" ::: "memory");
        __builtin_amdgcn_sched_barrier(0);
        if (chunk <= 13) STAGE(chunk & 1, chunk + 2);

        // split W -> A-fragments (hi, lo)
        FU ah, al;
        splitpk(ca.x, ca.y, ah.u[0], al.u[0]);
        splitpk(ca.z, ca.w, ah.u[1], al.u[1]);
        splitpk(cb.x, cb.y, ah.u[2], al.u[2]);
        splitpk(cb.z, cb.w, ah.u[3], al.u[3]);

        // u = W.x via 4-term bf16 split (smallest term first)
        f32x16 cf;
        #pragma unroll
        for (int i = 0; i < 16; ++i) cf[i] = 0.f;
        cf = __builtin_amdgcn_mfma_f32_32x32x16_bf16(al.s, bl.s, cf, 0, 0, 0);
        cf = __builtin_amdgcn_mfma_f32_32x32x16_bf16(ah.s, bl.s, cf, 0, 0, 0);
        cf = __builtin_amdgcn_mfma_f32_32x32x16_bf16(al.s, bh.s, cf, 0, 0, 0);
        cf = __builtin_amdgcn_mfma_f32_32x32x16_bf16(ah.s, bh.s, cf, 0, 0, 0);

        // softmax: Lv[b, r'] = sum_o u*v;  regs 0-7 are r'=0, 8-15 r'=1
        float Lp0 = 0.f, Lp1 = 0.f;
        #pragma unroll
        for (int reg = 0; reg < 8; ++reg)  Lp0 += cf[reg] * vf[reg];
        #pragma unroll
        for (int reg = 8; reg < 16; ++reg) Lp1 += cf[reg] * vf[reg];
        float Lv0 = Lp0 + __shfl_xor(Lp0, 32);     // partner has other 8 o's
        float Lv1 = Lp1 + __shfl_xor(Lp1, 32);
        float e0 = __expf(Lv0), e1 = __expf(Lv1);
        accZ += e0 + e1;                           // pair-duplicated (l<32 emits)
        #pragma unroll
        for (int reg = 0; reg < 8; ++reg)  accE[reg] += e0 * cf[reg];
        #pragma unroll
        for (int reg = 8; reg < 16; ++reg) accE[reg] += e1 * cf[reg];
    }
#undef STAGE

    // fold r' pairs (same o), reduce across waves via LDS atomics
    #pragma unroll
    for (int j = 0; j < 8; ++j) {
        int o = (j & 3) + 4 * hi + 8 * (j >> 2);
        atomicAdd(&E_lds[m * 16 + o], accE[j] + accE[j + 8]);
    }
    if (l < 32) atomicAdd(&Z_lds[m], accZ);
    __syncthreads();

    atomicAdd(&E[(tid >> 4) * 256 + c * 16 + (tid & 15)], E_lds[tid]);
    if (tid < 32) atomicAdd(&Z[tid * 16 + c], Z_lds[tid]);
}

// ---------------------------------------------------------------------------
// launch
// ---------------------------------------------------------------------------
extern "C" void kernel_launch(void* const* d_in, const int* in_sizes, int n_in,
                              void* d_out, int out_size, void* d_ws, size_t ws_size,
                              hipStream_t stream) {
    const float* x = (const float*)d_in[0];        // 8192 floats
    const float* W = (const float*)d_in[1];        // 67108864 floats (256 MB)
    float* out = (float*)d_out;                    // 8192 floats
    float* ws = (float*)d_ws;

    float* wsum = ws + 0;          // 4096
    float* E2   = ws + 4096;       // 8192
    float* Z2   = ws + 12288;      // 512
    float* E3   = ws + 12800;      // 8192
    float* Z3   = ws + 20992;      // 512   (accumulated region ends at 21504)
    float* v1   = ws + 21504;      // 8192
    float* vs   = ws + 29696;      // 8192  (v1 + v2, input to pass 3)

    // zero accumulators with our own kernel
    k_zero<<<84, 256, 0, stream>>>(ws);            // 84*256 = 21504 floats

    // iter 1: uniform softmax -> v1 from Wsum (W pass 1)
    k_wsum<<<1024, 256, 0, stream>>>((const float4*)W, wsum);
    k_v1<<<32, 256, 0, stream>>>(wsum, x, v1);

    // iter 2 fused: L2 = <u, v1>, E2/Z2 accumulated in-pass (W pass 2)
    k_iter<<<dim3(64, 16), 512, 0, stream>>>(W, x, v1, E2, Z2);
    k_vout_vs<<<32, 256, 0, stream>>>(E2, Z2, v1, vs);   // vs = v1 + squash(E2/Z2)

    // iter 3 fused: L3 = <u, v1+v2> (linearity: no history buffer needed)
    k_iter<<<dim3(64, 16), 512, 0, stream>>>(W, x, vs, E3, Z3);
    k_vout<<<32, 256, 0, stream>>>(E3, Z3, out);         // out = squash(E3/Z3)
}